// Round 1
// baseline (709.869 us; speedup 1.0000x reference)
//
#include <hip/hip_runtime.h>
#include <hip/hip_bf16.h>
#include <stdint.h>

// B=4, T=2048, C=1024, H=16, HS=64, FF=4096. N_tokens = 8192.

typedef unsigned short u16;
typedef __bf16 bf16x8 __attribute__((ext_vector_type(8)));
typedef float f32x4 __attribute__((ext_vector_type(4)));

#define MFMA16(a, b, c) __builtin_amdgcn_mfma_f32_16x16x32_bf16((a), (b), (c), 0, 0, 0)

__device__ __forceinline__ u16 f2bf(float f) {
  __hip_bfloat16 h = __float2bfloat16(f);
  return __builtin_bit_cast(u16, h);
}

__device__ __forceinline__ void gload16(const void* g, void* l) {
  __builtin_amdgcn_global_load_lds(
      (__attribute__((address_space(1))) void*)g,
      (__attribute__((address_space(3))) void*)l, 16, 0, 0);
}

// ---------------- LayerNorm: fp32 [rows][1024] -> bf16 ----------------
__global__ __launch_bounds__(256) void ln_kernel(
    const float* __restrict__ x, const float* __restrict__ g,
    const float* __restrict__ be, u16* __restrict__ out) {
  const int row = blockIdx.x;
  const int tid = threadIdx.x;
  const float4 v = reinterpret_cast<const float4*>(x + (size_t)row * 1024)[tid];
  float s = v.x + v.y + v.z + v.w;
  float s2 = v.x * v.x + v.y * v.y + v.z * v.z + v.w * v.w;
#pragma unroll
  for (int off = 1; off < 64; off <<= 1) {
    s += __shfl_xor(s, off);
    s2 += __shfl_xor(s2, off);
  }
  __shared__ float red[8];
  const int wid = tid >> 6;
  if ((tid & 63) == 0) { red[wid] = s; red[4 + wid] = s2; }
  __syncthreads();
  s = red[0] + red[1] + red[2] + red[3];
  s2 = red[4] + red[5] + red[6] + red[7];
  const float mu = s * (1.0f / 1024.0f);
  const float rstd = rsqrtf(s2 * (1.0f / 1024.0f) - mu * mu + 1e-5f);
  const float4 gv = reinterpret_cast<const float4*>(g)[tid];
  const float4 bv = reinterpret_cast<const float4*>(be)[tid];
  ushort4 o;
  o.x = f2bf((v.x - mu) * rstd * gv.x + bv.x);
  o.y = f2bf((v.y - mu) * rstd * gv.y + bv.y);
  o.z = f2bf((v.z - mu) * rstd * gv.z + bv.z);
  o.w = f2bf((v.w - mu) * rstd * gv.w + bv.w);
  *reinterpret_cast<ushort4*>(out + (size_t)row * 1024 + tid * 4) = o;
}

// ------- transpose+convert: src fp32 [R][C] -> dst bf16 [C][R], batched on z -------
__global__ __launch_bounds__(256) void tcvt(
    const float* __restrict__ src, u16* __restrict__ dst,
    int R, int C, size_t sstride, size_t dstride) {
  src += (size_t)blockIdx.z * sstride;
  dst += (size_t)blockIdx.z * dstride;
  __shared__ float t[64][65];
  const int r0 = blockIdx.x * 64, c0 = blockIdx.y * 64;
  const int tid = threadIdx.x;
  const int cc = tid & 63, rr = tid >> 6;  // rr: 0..3
#pragma unroll
  for (int p = 0; p < 16; ++p) {
    const int r = rr + p * 4;
    t[r][cc] = src[(size_t)(r0 + r) * C + c0 + cc];
  }
  __syncthreads();
#pragma unroll
  for (int p = 0; p < 16; ++p) {
    const int c = rr + p * 4;
    dst[(size_t)(c0 + c) * R + r0 + cc] = f2bf(t[cc][c]);
  }
}

// ---------------- GEMM: A bf16 [M][K] x Bt bf16 [N][K] -> epilogue ----------------
// 128x128 tile, BK=32, 4 waves (2x2), each wave 64x64 = 4x4 MFMA frags.
// LDS XOR-swizzle (slot ^= (row>>1)&3) applied on BOTH the pre-swizzled global
// source (linear global_load_lds dest) and the ds_read address -> involution.
constexpr int EPI_QKV = 0;   // scatter to q/k/v [BH][T][HS] bf16
constexpr int EPI_RES = 1;   // fp32 out = acc + bias[n] + res[idx]
constexpr int EPI_RELU = 2;  // bf16 out = relu(acc + bias[n])

template <int EPI>
__global__ __launch_bounds__(256) void gemm_bf16(
    const u16* __restrict__ A, const u16* __restrict__ Bt,
    int M, int N, int K,
    u16* outB, float* outF, const float* bias, const float* res) {
  __shared__ u16 sA[128 * 32] __attribute__((aligned(16)));
  __shared__ u16 sB[128 * 32] __attribute__((aligned(16)));
  const int tid = threadIdx.x;
  const int lane = tid & 63, wid = tid >> 6;
  const int bm = blockIdx.x, bn = blockIdx.y;
  const int wr = wid >> 1, wc = wid & 1;
  const int l16 = lane & 15, lg = lane >> 4;

  f32x4 acc[4][4];
#pragma unroll
  for (int m = 0; m < 4; ++m)
#pragma unroll
    for (int n = 0; n < 4; ++n) {
      acc[m][n][0] = 0.f; acc[m][n][1] = 0.f; acc[m][n][2] = 0.f; acc[m][n][3] = 0.f;
    }

  const size_t rowA = (size_t)bm * 128;
  const size_t rowB = (size_t)bn * 128;
  const int nkt = K >> 5;

  for (int kt = 0; kt < nkt; ++kt) {
    const int k0 = kt * 32;
#pragma unroll
    for (int it = 0; it < 2; ++it) {
      const int f = tid + it * 256;          // LDS 16B-chunk index
      const int r = f >> 2;                  // tile row
      const int sl = (f & 3) ^ ((r >> 1) & 3);  // pre-swizzled source slot
      gload16(A + (rowA + r) * K + k0 + sl * 8, (char*)sA + wid * 1024 + it * 4096);
      gload16(Bt + (rowB + r) * K + k0 + sl * 8, (char*)sB + wid * 1024 + it * 4096);
    }
    __syncthreads();
    bf16x8 af[4], bfr[4];
#pragma unroll
    for (int m = 0; m < 4; ++m) {
      const int r = wr * 64 + m * 16 + l16;
      const int sl = lg ^ ((r >> 1) & 3);
      af[m] = *reinterpret_cast<const bf16x8*>(sA + r * 32 + sl * 8);
    }
#pragma unroll
    for (int n = 0; n < 4; ++n) {
      const int r = wc * 64 + n * 16 + l16;
      const int sl = lg ^ ((r >> 1) & 3);
      bfr[n] = *reinterpret_cast<const bf16x8*>(sB + r * 32 + sl * 8);
    }
#pragma unroll
    for (int m = 0; m < 4; ++m)
#pragma unroll
      for (int n = 0; n < 4; ++n)
        acc[m][n] = MFMA16(af[m], bfr[n], acc[m][n]);
    __syncthreads();
  }

#pragma unroll
  for (int m = 0; m < 4; ++m)
#pragma unroll
    for (int n = 0; n < 4; ++n)
#pragma unroll
      for (int ii = 0; ii < 4; ++ii) {
        const int gi = bm * 128 + wr * 64 + m * 16 + lg * 4 + ii;
        const int gj = bn * 128 + wc * 64 + n * 16 + l16;
        const float val = acc[m][n][ii];
        if constexpr (EPI == EPI_QKV) {
          const int sel = gj >> 10;          // 0:q 1:k 2:v
          const int hh = (gj >> 6) & 15;
          const int dd = gj & 63;
          const int bb = gi >> 11, tt = gi & 2047;
          outB[(size_t)sel * 8388608 + ((size_t)(bb * 16 + hh) * 2048 + tt) * 64 + dd] = f2bf(val);
        } else if constexpr (EPI == EPI_RES) {
          const size_t idx = (size_t)gi * N + gj;
          outF[idx] = val + bias[gj] + res[idx];
        } else {  // EPI_RELU
          const float b = val + bias[gj];
          outB[(size_t)gi * N + gj] = f2bf(b > 0.f ? b : 0.f);
        }
      }
}

// ---------------- causal flash attention ----------------
// grid (32 qtiles, 64 bh). 4 waves x 16 q-rows. K/V tiles of 64.
__global__ __launch_bounds__(256) void attn_kernel(
    const u16* __restrict__ q, const u16* __restrict__ k,
    const u16* __restrict__ v, u16* __restrict__ o) {
  const int qt = gridDim.x - 1 - blockIdx.x;  // heavy tiles first
  const int bh = blockIdx.y;
  const int tid = threadIdx.x;
  const int lane = tid & 63, wid = tid >> 6;
  const int l16 = lane & 15, lg = lane >> 4;
  const u16* qb = q + (size_t)bh * 2048 * 64;
  const u16* kb = k + (size_t)bh * 2048 * 64;
  const u16* vb = v + (size_t)bh * 2048 * 64;
  const int q0 = qt * 64;

  __shared__ u16 sVt[64][72] __attribute__((aligned(16)));     // V^T tile [d][kv]
  __shared__ u16 sP[4][16][72] __attribute__((aligned(16)));   // per-wave P

  bf16x8 aq[2];
#pragma unroll
  for (int kk = 0; kk < 2; ++kk)
    aq[kk] = *reinterpret_cast<const bf16x8*>(
        qb + (size_t)(q0 + wid * 16 + l16) * 64 + kk * 32 + lg * 8);

  f32x4 oacc[4];
#pragma unroll
  for (int nt = 0; nt < 4; ++nt) { oacc[nt][0]=0.f; oacc[nt][1]=0.f; oacc[nt][2]=0.f; oacc[nt][3]=0.f; }
  float mi[4] = {-1e30f, -1e30f, -1e30f, -1e30f};
  float li[4] = {0.f, 0.f, 0.f, 0.f};
  const float scale = 0.125f;  // 1/sqrt(64)

  for (int ks = 0; ks <= qt; ++ks) {
    const int s0 = ks * 64;
    __syncthreads();  // prior-iter reads of sVt done
    // stage V^T: lanes write consecutive kv (u16-contiguous -> conflict-free)
#pragma unroll
    for (int it = 0; it < 2; ++it) {
      const int f = tid + it * 256;
      const int kv = f & 63;
      const int d8 = (f >> 6) * 8;
      uint4 tmp = *reinterpret_cast<const uint4*>(vb + (size_t)(s0 + kv) * 64 + d8);
      const u16* e = reinterpret_cast<const u16*>(&tmp);
#pragma unroll
      for (int j = 0; j < 8; ++j) sVt[d8 + j][kv] = e[j];
    }
    __syncthreads();

    // S = Q K^T  (K rows read as B-fragments of K^T)
    f32x4 sc[4];
#pragma unroll
    for (int nt = 0; nt < 4; ++nt) { sc[nt][0]=0.f; sc[nt][1]=0.f; sc[nt][2]=0.f; sc[nt][3]=0.f; }
#pragma unroll
    for (int kk = 0; kk < 2; ++kk)
#pragma unroll
      for (int nt = 0; nt < 4; ++nt) {
        bf16x8 bk = *reinterpret_cast<const bf16x8*>(
            kb + (size_t)(s0 + nt * 16 + l16) * 64 + kk * 32 + lg * 8);
        sc[nt] = MFMA16(aq[kk], bk, sc[nt]);
      }

    // online softmax. D row = lg*4+ii (stats align with lane group).
    const bool diag = (ks == qt);
    float sv[4][4];
    float pm[4] = {-3e38f, -3e38f, -3e38f, -3e38f};
#pragma unroll
    for (int nt = 0; nt < 4; ++nt)
#pragma unroll
      for (int ii = 0; ii < 4; ++ii) {
        float xv = sc[nt][ii] * scale;
        if (diag && (nt * 16 + l16 > wid * 16 + lg * 4 + ii)) xv = -1e30f;
        sv[ii][nt] = xv;
        pm[ii] = fmaxf(pm[ii], xv);
      }
#pragma unroll
    for (int off = 1; off < 16; off <<= 1)
#pragma unroll
      for (int ii = 0; ii < 4; ++ii) pm[ii] = fmaxf(pm[ii], __shfl_xor(pm[ii], off));
    float al[4];
#pragma unroll
    for (int ii = 0; ii < 4; ++ii) {
      const float mn = fmaxf(mi[ii], pm[ii]);
      al[ii] = __expf(mi[ii] - mn);
      mi[ii] = mn;
    }
    float rs[4] = {0.f, 0.f, 0.f, 0.f};
#pragma unroll
    for (int nt = 0; nt < 4; ++nt)
#pragma unroll
      for (int ii = 0; ii < 4; ++ii) {
        const float p = __expf(sv[ii][nt] - mi[ii]);
        sv[ii][nt] = p;
        rs[ii] += p;
      }
#pragma unroll
    for (int off = 1; off < 16; off <<= 1)
#pragma unroll
      for (int ii = 0; ii < 4; ++ii) rs[ii] += __shfl_xor(rs[ii], off);
#pragma unroll
    for (int ii = 0; ii < 4; ++ii) li[ii] = li[ii] * al[ii] + rs[ii];
#pragma unroll
    for (int nt = 0; nt < 4; ++nt)
#pragma unroll
      for (int ii = 0; ii < 4; ++ii) oacc[nt][ii] *= al[ii];

    // P (D-layout) -> LDS -> A-fragments (intra-wave, no barrier needed)
#pragma unroll
    for (int ii = 0; ii < 4; ++ii)
#pragma unroll
      for (int nt = 0; nt < 4; ++nt)
        sP[wid][lg * 4 + ii][nt * 16 + l16] = f2bf(sv[ii][nt]);
    bf16x8 ap[2];
#pragma unroll
    for (int kk = 0; kk < 2; ++kk)
      ap[kk] = *reinterpret_cast<const bf16x8*>(&sP[wid][l16][kk * 32 + lg * 8]);
#pragma unroll
    for (int kk = 0; kk < 2; ++kk)
#pragma unroll
      for (int nt = 0; nt < 4; ++nt) {
        bf16x8 bv2 = *reinterpret_cast<const bf16x8*>(&sVt[nt * 16 + l16][kk * 32 + lg * 8]);
        oacc[nt] = MFMA16(ap[kk], bv2, oacc[nt]);
      }
  }

  const int bb = bh >> 4, hh = bh & 15;
#pragma unroll
  for (int nt = 0; nt < 4; ++nt)
#pragma unroll
    for (int ii = 0; ii < 4; ++ii) {
      const float val = oacc[nt][ii] / li[ii];
      o[((size_t)(bb * 2048 + q0 + wid * 16 + lg * 4 + ii)) * 1024 + hh * 64 + nt * 16 + l16] =
          f2bf(val);
    }
}

// ---------------- host launch ----------------
extern "C" void kernel_launch(void* const* d_in, const int* in_sizes, int n_in,
                              void* d_out, int out_size, void* d_ws, size_t ws_size,
                              hipStream_t stream) {
  const float* x = (const float*)d_in[0];
  const float* Wq = (const float*)d_in[1];
  const float* Wk = (const float*)d_in[2];
  const float* Wv = (const float*)d_in[3];
  const float* Wproj = (const float*)d_in[4];
  const float* bproj = (const float*)d_in[5];
  const float* W1 = (const float*)d_in[6];
  const float* b1 = (const float*)d_in[7];
  const float* W2 = (const float*)d_in[8];
  const float* b2 = (const float*)d_in[9];
  const float* g1 = (const float*)d_in[10];
  const float* be1 = (const float*)d_in[11];
  const float* g2 = (const float*)d_in[12];
  const float* be2 = (const float*)d_in[13];
  float* out = (float*)d_out;

  char* ws = (char*)d_ws;
  const size_t MB16 = 16777216ull;
  u16* hb = (u16*)(ws);                 // 16MB: ln out (reused for ln2 out)
  u16* qkv = (u16*)(ws + MB16);         // 48MB: q,k,v each 8388608 elems
  u16* qp = qkv;
  u16* kp = qkv + 8388608;
  u16* vp = qkv + 2 * 8388608;
  u16* ab = (u16*)(ws + 4 * MB16);      // 16MB: attention out [B,T,C]
  u16* f1 = qkv;                        // 64MB reuse (16MB..80MB) for relu(ff1)
  u16* wqkvt = (u16*)(ws + 5 * MB16);   // 6MB  [3072][1024]
  u16* wprojt = wqkvt + 3145728;        // 2MB  [1024][1024]
  u16* w1t = wprojt + 1048576;          // 8MB  [4096][1024]
  u16* w2t = w1t + 4194304;             // 8MB  [1024][4096]

  dim3 blk(256);
  // weight convert+transpose (per-head transpose for Wq/Wk/Wv)
  tcvt<<<dim3(16, 1, 16), blk, 0, stream>>>(Wq, wqkvt, 1024, 64, 65536, 65536);
  tcvt<<<dim3(16, 1, 16), blk, 0, stream>>>(Wk, wqkvt + 1048576, 1024, 64, 65536, 65536);
  tcvt<<<dim3(16, 1, 16), blk, 0, stream>>>(Wv, wqkvt + 2097152, 1024, 64, 65536, 65536);
  tcvt<<<dim3(16, 16, 1), blk, 0, stream>>>(Wproj, wprojt, 1024, 1024, 0, 0);
  tcvt<<<dim3(16, 64, 1), blk, 0, stream>>>(W1, w1t, 1024, 4096, 0, 0);
  tcvt<<<dim3(64, 16, 1), blk, 0, stream>>>(W2, w2t, 4096, 1024, 0, 0);

  ln_kernel<<<8192, blk, 0, stream>>>(x, g1, be1, hb);
  gemm_bf16<EPI_QKV><<<dim3(64, 24), blk, 0, stream>>>(hb, wqkvt, 8192, 3072, 1024,
                                                       qkv, nullptr, nullptr, nullptr);
  attn_kernel<<<dim3(32, 64), blk, 0, stream>>>(qp, kp, vp, ab);
  gemm_bf16<EPI_RES><<<dim3(64, 8), blk, 0, stream>>>(ab, wprojt, 8192, 1024, 1024,
                                                      nullptr, out, bproj, x);
  ln_kernel<<<8192, blk, 0, stream>>>(out, g2, be2, hb);
  gemm_bf16<EPI_RELU><<<dim3(64, 32), blk, 0, stream>>>(hb, w1t, 8192, 4096, 1024,
                                                        f1, nullptr, b1, nullptr);
  gemm_bf16<EPI_RES><<<dim3(64, 8), blk, 0, stream>>>(f1, w2t, 8192, 1024, 4096,
                                                      nullptr, out, b2, out);
}